// Round 11
// baseline (16335.393 us; speedup 1.0000x reference)
//
#include <hip/hip_runtime.h>
#include <hip/hip_bf16.h>
#include <cstdint>
#include <cstddef>

#define BB 64
#define TT 512
#define DD 1024
#define HH 2048
#define GG 8192   // 4*H

typedef unsigned short u16;
typedef __attribute__((ext_vector_type(8))) short bf16x8;
typedef __attribute__((ext_vector_type(4))) float f32x4;

__device__ __forceinline__ u16 f2bf(float f) {
  union { float f; uint32_t u; } v; v.f = f;
  uint32_t r = v.u + 0x7FFFu + ((v.u >> 16) & 1u);  // RNE
  return (u16)(r >> 16);
}
__device__ __forceinline__ float bf2f(u16 h) {
  union { uint32_t u; float f; } v; v.u = ((uint32_t)h) << 16; return v.f;
}

__device__ __forceinline__ bf16x8 cvt8(const float* __restrict__ p) {
  float4 a = *(const float4*)p;
  float4 b = *(const float4*)(p + 4);
  bf16x8 r;
  r[0] = (short)f2bf(a.x); r[1] = (short)f2bf(a.y);
  r[2] = (short)f2bf(a.z); r[3] = (short)f2bf(a.w);
  r[4] = (short)f2bf(b.x); r[5] = (short)f2bf(b.y);
  r[6] = (short)f2bf(b.z); r[7] = (short)f2bf(b.w);
  return r;
}

// fully-coherent 16B ops (bypass L1+L2, served at coherence point) — PROVEN r5/r9
__device__ __forceinline__ bf16x8 cohload16(const u16* p) {
  bf16x8 v;
  asm volatile("global_load_dwordx4 %0, %1, off sc0 sc1" : "=v"(v) : "v"(p));
  return v;
}
__device__ __forceinline__ void cohstore16(u16* p, bf16x8 v) {
  asm volatile("global_store_dwordx4 %0, %1, off sc0 sc1" :: "v"(p), "v"(v) : "memory");
}
__device__ __forceinline__ int get_xcd() {
  int x;
  asm("s_getreg_b32 %0, hwreg(20, 0, 32)" : "=s"(x));   // HW_REG_XCC_ID
  return x & 7;
}

// ---- preps ----
__global__ void conv_wih_kernel(const float* __restrict__ W, u16* __restrict__ Wb) {
  size_t idx = (size_t)blockIdx.x * blockDim.x + threadIdx.x;
  if (idx >= (size_t)GG * DD / 8) return;
  *(bf16x8*)(Wb + idx * 8) = cvt8(W + idx * 8);
}

// x: [B][T][D] fp32 -> xbT: [T][B][D] bf16
__global__ void conv_xT_kernel(const float* __restrict__ x, u16* __restrict__ xbT) {
  size_t idx = (size_t)blockIdx.x * blockDim.x + threadIdx.x;
  if (idx >= (size_t)BB * TT * DD / 8) return;
  const int col8 = (int)(idx & 127);
  const int row = (int)(idx >> 7);          // b*512 + t
  const int b = row >> 9, t = row & 511;
  bf16x8 v = cvt8(x + (size_t)row * DD + col8 * 8);
  *(bf16x8*)(xbT + ((size_t)t * BB + b) * DD + col8 * 8) = v;
}

// ======================= persistent LSTM (partial-exchange) =======================
// XCD x owns hidden cols Kx=[256x,256x+256). Its 32 CUs hold W_hh[:,Kx] in REGS
// (256 rows x 256 k per CU), compute bf16 partials for all 8192 gate rows over
// k in Kx, cohstore them (32KB/CU -> 8MB/step fabric), and reduce partials for
// THEIR OWN rows (8-way sum + x-part + bias). h[:,Kx] then stays XCD-LOCAL:
// plain stores to own L2, plain-load flags with buffer_inv sc0 (same-L2 safe).
// Cross-XCD sync: pflag agent atomics (proven) gating cohload of partials.
// Parity-2 buffers; max skew 1 (happens-before chains in round notes).
template<int XMODE>   // 1: x from xbT [T,B,D] bf16; 0: x fp32 [B,T,D] direct
__global__ __launch_bounds__(512, 1)
void lstm_persistent(const float* __restrict__ x, const u16* __restrict__ xbT,
                     const u16* __restrict__ wihb, const float* __restrict__ W_hh,
                     const float* __restrict__ b_ih, const float* __restrict__ b_hh,
                     u16* __restrict__ Lh, int* __restrict__ pflag,
                     int* __restrict__ lhflag, int* __restrict__ xcdcnt,
                     u16* __restrict__ Pbuf) {
  __shared__ u16 pstage[64 * 264];        // 33 KB  [b][256+pad] bf16 partials
  __shared__ u16 pr[8 * 4 * 64 * 8];      // 32 KB  [y][m][b][jl] imported partials
  __shared__ float xstage[32 * 66];       // 8.25 KB [xrow][b+pad] x-part fp32
  __shared__ char occ_pad[32768];         // force 1 WG/CU (LDS > 80 KB)
  __shared__ int sxcd, srank;

  const int tid = threadIdx.x;
  const int wave = tid >> 6, lane = tid & 63;
  const int c16 = lane & 15, lofs = lane >> 4;

  if (tid == 0) {
    const int xd = get_xcd();
    sxcd = xd;
    srank = __hip_atomic_fetch_add(xcdcnt + xd * 16, 1, __ATOMIC_RELAXED,
                                   __HIP_MEMORY_SCOPE_AGENT);
  }
  __syncthreads();
  const int xcd = sxcd, rank = srank & 31;
  if (xcd > 8) occ_pad[0] = 1;            // never true; keeps pad resident

  // ---- one-time: W_hh slice -> REGISTERS (256 rows x 256 k per CU) ----
  bf16x8 Wreg[2][8];
  {
    const int growb = 256 * rank + wave * 32;
    #pragma unroll
    for (int nt2 = 0; nt2 < 2; ++nt2)
      #pragma unroll
      for (int kb = 0; kb < 8; ++kb)
        Wreg[nt2][kb] = cvt8(W_hh + (size_t)(growb + nt2 * 16 + c16) * HH
                                   + 256 * xcd + kb * 32 + lofs * 8);
  }

  // x-part identity: wave (ng, mt4); W_ih row for lane
  const int ng = wave & 1, mt4 = wave >> 1;
  const int xrow = ng * 16 + c16;                       // 0..31
  const int xg = (xrow >> 3) * HH + 256 * xcd + 8 * rank + (xrow & 7);
  const u16* wihrow = wihb + (size_t)xg * DD;

  // epilogue identity
  const int eb = tid >> 3, ejl = tid & 7;
  const int jg = 256 * xcd + 8 * rank + ejl;
  const float bi0 = b_ih[jg] + b_hh[jg];
  const float bi1 = b_ih[HH + jg] + b_hh[HH + jg];
  const float bi2 = b_ih[2 * HH + jg] + b_hh[2 * HH + jg];
  const float bi3 = b_ih[3 * HH + jg] + b_hh[3 * HH + jg];
  float cst = 0.f;

  const int xdst = rank & 7, mprod = rank >> 3;         // producer dest XCD / gate
  int* myPflag = pflag + (xcd * 32 + rank) * 16;
  int* myLhflag = lhflag + (xcd * 32 + rank) * 16;

  for (int t = 0; t < TT; ++t) {
    const int pp = t & 1, pread = pp ^ 1, pwrite = pp;

    // ---- phase 1: x-part (h-independent, overlaps everything) ----
    {
      f32x4 xacc = {0.f, 0.f, 0.f, 0.f};
      const size_t aoff = XMODE ? ((size_t)(t * BB + mt4 * 16 + c16) * DD)
                                : (((size_t)(mt4 * 16 + c16) * TT + t) * DD);
      #pragma unroll 8
      for (int kb = 0; kb < 32; ++kb) {
        const int k = kb * 32 + lofs * 8;
        bf16x8 a;
        if constexpr (XMODE == 1) a = *(const bf16x8*)(xbT + aoff + k);
        else                      a = cvt8(x + aoff + k);
        bf16x8 bf = *(const bf16x8*)(wihrow + k);
        xacc = __builtin_amdgcn_mfma_f32_16x16x32_bf16(a, bf, xacc, 0, 0, 0);
      }
      #pragma unroll
      for (int q = 0; q < 4; ++q)
        xstage[xrow * 66 + mt4 * 16 + lofs * 4 + q] = xacc[q];
    }

    // ---- phase 2: local-h gate (same-L2 plain flags; wave 0 polls) ----
    if (t > 0 && wave == 0) {
      const int* fl = lhflag + (xcd * 32 + (lane & 31)) * 16;
      int iters = 0;
      while (true) {
        asm volatile("buffer_inv sc0" ::: "memory");
        int v;
        asm volatile("global_load_dword %0, %1, off\n\ts_waitcnt vmcnt(0)"
                     : "=v"(v) : "v"(fl) : "memory");
        if (__all(v >= t)) break;
        __builtin_amdgcn_s_sleep(2);
        if (++iters > (1 << 17)) break;   // fail loud, never hang
      }
      asm volatile("buffer_inv sc0" ::: "memory");   // drop stale Lh L1 lines
    }
    __syncthreads();

    // ---- phase 3: partial GEMM (A = local h slice, B = Wreg) ----
    {
      f32x4 pacc[4][2] = {};
      const u16* lhb = Lh + ((size_t)(xcd * 2 + pread) * 64) * 256;
      #pragma unroll
      for (int kb = 0; kb < 8; ++kb) {
        bf16x8 af[4];
        #pragma unroll
        for (int mt = 0; mt < 4; ++mt)
          af[mt] = *(const bf16x8*)(lhb + (size_t)(mt * 16 + c16) * 256 + kb * 32 + lofs * 8);
        #pragma unroll
        for (int mt = 0; mt < 4; ++mt) {
          pacc[mt][0] = __builtin_amdgcn_mfma_f32_16x16x32_bf16(af[mt], Wreg[0][kb], pacc[mt][0], 0, 0, 0);
          pacc[mt][1] = __builtin_amdgcn_mfma_f32_16x16x32_bf16(af[mt], Wreg[1][kb], pacc[mt][1], 0, 0, 0);
        }
      }
      #pragma unroll
      for (int mt = 0; mt < 4; ++mt)
        #pragma unroll
        for (int nt2 = 0; nt2 < 2; ++nt2)
          #pragma unroll
          for (int q = 0; q < 4; ++q)
            pstage[(mt * 16 + lofs * 4 + q) * 264 + wave * 32 + nt2 * 16 + c16]
                = f2bf(pacc[mt][nt2][q]);
    }
    __syncthreads();

    // ---- phase 4: export partials (cohstore, 32 KB/CU) + pflag ----
    {
      const int jc = tid >> 4, b0 = (tid & 15) * 4;
      u16* dst = Pbuf + ((size_t)(xdst * 2 + pp) << 19)
                      + (size_t)((jc * 8 + xcd) * 4 + mprod) * 512;
      #pragma unroll
      for (int i = 0; i < 4; ++i) {
        const int b = b0 + i;
        bf16x8 v = *(const bf16x8*)(pstage + b * 264 + jc * 8);
        cohstore16(dst + b * 8, v);
      }
      asm volatile("s_waitcnt vmcnt(0)" ::: "memory");
    }
    __syncthreads();
    if (tid == 0)
      __hip_atomic_store(myPflag, t + 1, __ATOMIC_RELAXED, __HIP_MEMORY_SCOPE_AGENT);

    // ---- phase 5: gate on 32 sources (wave 0) + import 32 KB to pr ----
    if (wave == 0) {
      const int l2 = lane & 31;
      const int* sfl = pflag + ((l2 >> 2) * 32 + (l2 & 3) * 8 + xcd) * 16;
      int iters = 0;
      while (true) {
        int v = __hip_atomic_load(sfl, __ATOMIC_RELAXED, __HIP_MEMORY_SCOPE_AGENT);
        if (__all(v >= t + 1)) break;
        __builtin_amdgcn_s_sleep(2);
        if (++iters > (1 << 17)) break;
      }
    }
    __syncthreads();
    {
      const u16* src = Pbuf + ((size_t)(xcd * 2 + pp) << 19) + (size_t)rank * 16384;
      bf16x8 v0 = cohload16(src + (0 * 512 + tid) * 8);
      bf16x8 v1 = cohload16(src + (1 * 512 + tid) * 8);
      bf16x8 v2 = cohload16(src + (2 * 512 + tid) * 8);
      bf16x8 v3 = cohload16(src + (3 * 512 + tid) * 8);
      asm volatile("s_waitcnt vmcnt(0)" ::: "memory");
      __builtin_amdgcn_sched_barrier(0);
      *(bf16x8*)(pr + (0 * 512 + tid) * 8) = v0;
      *(bf16x8*)(pr + (1 * 512 + tid) * 8) = v1;
      *(bf16x8*)(pr + (2 * 512 + tid) * 8) = v2;
      *(bf16x8*)(pr + (3 * 512 + tid) * 8) = v3;
    }
    __syncthreads();

    // ---- phase 6: reduce + gates + publish local h ----
    {
      float g4[4];
      #pragma unroll
      for (int m = 0; m < 4; ++m) {
        float s = 0.f;
        #pragma unroll
        for (int y = 0; y < 8; ++y)
          s += bf2f(pr[((y * 4 + m) * 64 + eb) * 8 + ejl]);
        g4[m] = s + xstage[(m * 8 + ejl) * 66 + eb];
      }
      const float ig = 1.f / (1.f + expf(-(g4[0] + bi0)));
      const float fg = 1.f / (1.f + expf(-(g4[1] + bi1)));
      const float gv = tanhf(g4[2] + bi2);
      const float og = 1.f / (1.f + expf(-(g4[3] + bi3)));
      cst = fg * cst + ig * gv;
      const uint32_t hv = (uint32_t)f2bf(og * tanhf(cst));
      u16* hp = Lh + ((size_t)(xcd * 2 + pwrite) * 64 + eb) * 256 + 8 * rank + ejl;
      asm volatile("global_store_short %0, %1, off" :: "v"(hp), "v"(hv) : "memory");
      asm volatile("s_waitcnt vmcnt(0)" ::: "memory");
    }
    __syncthreads();
    if (tid == 0) {
      const int tv = t + 1;
      asm volatile("global_store_dword %0, %1, off" :: "v"(myLhflag), "v"(tv) : "memory");
    }
  }
}

// ======================= head (reads Lh slices, parity 1) =======================
__global__ __launch_bounds__(256)
void head_lh_kernel(const u16* __restrict__ Lh, const float* __restrict__ W_head,
                    const float* __restrict__ b_head, float* __restrict__ out) {
  const int tid = threadIdx.x, wave = tid >> 6, lane = tid & 63;
  const int m = wave;
  const int c = lane & 15;
  const int koff = (lane >> 4) * 8;
  const int d = blockIdx.x * 16 + c;
  const int arow = m * 16 + c;
  f32x4 acc = {0.f, 0.f, 0.f, 0.f};
  #pragma unroll 4
  for (int kb = 0; kb < 64; ++kb) {
    const int k = kb * 32 + koff;
    const int xk = k >> 8, jloc = k & 255;
    bf16x8 a = *(const bf16x8*)(Lh + ((size_t)(xk * 2 + 1) * 64 + arow) * 256 + jloc);
    bf16x8 b = cvt8(W_head + (size_t)d * HH + k);
    acc = __builtin_amdgcn_mfma_f32_16x16x32_bf16(a, b, acc, 0, 0, 0);
  }
  const float bh = b_head[d];
  #pragma unroll
  for (int q = 0; q < 4; ++q) {
    const int b = m * 16 + (lane >> 4) * 4 + q;
    out[(size_t)b * DD + d] = acc[q] + bh;
  }
}

// ======================= fallback per-step kernel (round-1 proven) =======================
__global__ __launch_bounds__(512)
void lstm_step_kernel(const float* __restrict__ x,
                      const float* __restrict__ W_ih, const float* __restrict__ W_hh,
                      const float* __restrict__ b_ih, const float* __restrict__ b_hh,
                      const u16* __restrict__ h_src, u16* __restrict__ h_dst,
                      float* __restrict__ cbuf, int t) {
  const int tid = threadIdx.x;
  const int wave = tid >> 6, lane = tid & 63;
  const int m = wave & 3, khalf = wave >> 2;
  const int j0 = blockIdx.x * 8;
  const int c = lane & 15;
  const int arow = m * 16 + c;
  const int koff = (lane >> 4) * 8;
  const int r0 = (c < 8) ? (j0 + c) : (HH + j0 + c - 8);
  const int r1 = (c < 8) ? (2 * HH + j0 + c) : (3 * HH + j0 + c - 8);

  f32x4 acc0 = {0.f, 0.f, 0.f, 0.f};
  f32x4 acc1 = {0.f, 0.f, 0.f, 0.f};

  if (khalf == 0) {
    const size_t xrow = ((size_t)arow * TT + t) * DD;
    #pragma unroll 4
    for (int kb = 0; kb < 32; ++kb) {
      const int k = kb * 32 + koff;
      bf16x8 a = cvt8(x + xrow + k);
      bf16x8 b0 = cvt8(W_ih + (size_t)r0 * DD + k);
      bf16x8 b1 = cvt8(W_ih + (size_t)r1 * DD + k);
      acc0 = __builtin_amdgcn_mfma_f32_16x16x32_bf16(a, b0, acc0, 0, 0, 0);
      acc1 = __builtin_amdgcn_mfma_f32_16x16x32_bf16(a, b1, acc1, 0, 0, 0);
    }
    #pragma unroll 4
    for (int kb = 0; kb < 16; ++kb) {
      const int kh = kb * 32 + koff;
      bf16x8 a = *(const bf16x8*)(h_src + (size_t)arow * HH + kh);
      bf16x8 b0 = cvt8(W_hh + (size_t)r0 * HH + kh);
      bf16x8 b1 = cvt8(W_hh + (size_t)r1 * HH + kh);
      acc0 = __builtin_amdgcn_mfma_f32_16x16x32_bf16(a, b0, acc0, 0, 0, 0);
      acc1 = __builtin_amdgcn_mfma_f32_16x16x32_bf16(a, b1, acc1, 0, 0, 0);
    }
  } else {
    #pragma unroll 4
    for (int kb = 0; kb < 48; ++kb) {
      const int kh = 512 + kb * 32 + koff;
      bf16x8 a = *(const bf16x8*)(h_src + (size_t)arow * HH + kh);
      bf16x8 b0 = cvt8(W_hh + (size_t)r0 * HH + kh);
      bf16x8 b1 = cvt8(W_hh + (size_t)r1 * HH + kh);
      acc0 = __builtin_amdgcn_mfma_f32_16x16x32_bf16(a, b0, acc0, 0, 0, 0);
      acc1 = __builtin_amdgcn_mfma_f32_16x16x32_bf16(a, b1, acc1, 0, 0, 0);
    }
  }

  __shared__ float red[4][2][64][4];
  if (khalf == 1) {
    #pragma unroll
    for (int q = 0; q < 4; ++q) { red[m][0][lane][q] = acc0[q]; red[m][1][lane][q] = acc1[q]; }
  }
  __syncthreads();
  if (khalf == 1) return;
  #pragma unroll
  for (int q = 0; q < 4; ++q) { acc0[q] += red[m][0][lane][q]; acc1[q] += red[m][1][lane][q]; }

  const float bias0 = b_ih[r0] + b_hh[r0];
  const float bias1 = b_ih[r1] + b_hh[r1];
  #pragma unroll
  for (int q = 0; q < 4; ++q) { acc0[q] += bias0; acc1[q] += bias1; }

  float fpre[4], opre[4];
  #pragma unroll
  for (int q = 0; q < 4; ++q) {
    fpre[q] = __shfl_xor(acc0[q], 8);
    opre[q] = __shfl_xor(acc1[q], 8);
  }

  if (c < 8) {
    const int j = j0 + c;
    #pragma unroll
    for (int q = 0; q < 4; ++q) {
      const int b = m * 16 + (lane >> 4) * 4 + q;
      const float ig = 1.f / (1.f + expf(-acc0[q]));
      const float fg = 1.f / (1.f + expf(-fpre[q]));
      const float gg = tanhf(acc1[q]);
      const float og = 1.f / (1.f + expf(-opre[q]));
      const float cold = cbuf[(size_t)b * HH + j];
      const float cn = fg * cold + ig * gg;
      cbuf[(size_t)b * HH + j] = cn;
      h_dst[(size_t)b * HH + j] = f2bf(og * tanhf(cn));
    }
  }
}

// old flat head for fallback path
__global__ __launch_bounds__(256)
void head_kernel(const u16* __restrict__ hfin, const float* __restrict__ W_head,
                 const float* __restrict__ b_head, float* __restrict__ out) {
  const int tid = threadIdx.x, wave = tid >> 6, lane = tid & 63;
  const int m = wave;
  const int c = lane & 15;
  const int koff = (lane >> 4) * 8;
  const int d = blockIdx.x * 16 + c;
  const int arow = m * 16 + c;
  f32x4 acc = {0.f, 0.f, 0.f, 0.f};
  #pragma unroll 4
  for (int kb = 0; kb < 64; ++kb) {
    const int k = kb * 32 + koff;
    bf16x8 a = *(const bf16x8*)(hfin + (size_t)arow * HH + k);
    bf16x8 b = cvt8(W_head + (size_t)d * HH + k);
    acc = __builtin_amdgcn_mfma_f32_16x16x32_bf16(a, b, acc, 0, 0, 0);
  }
  const float bh = b_head[d];
  #pragma unroll
  for (int q = 0; q < 4; ++q) {
    const int b = m * 16 + (lane >> 4) * 4 + q;
    out[(size_t)b * DD + d] = acc[q] + bh;
  }
}

extern "C" void kernel_launch(void* const* d_in, const int* in_sizes, int n_in,
                              void* d_out, int out_size, void* d_ws, size_t ws_size,
                              hipStream_t stream) {
  const float* x      = (const float*)d_in[0];
  const float* W_ih   = (const float*)d_in[1];
  const float* W_hh   = (const float*)d_in[2];
  const float* b_ih   = (const float*)d_in[3];
  const float* b_hh   = (const float*)d_in[4];
  const float* W_head = (const float*)d_in[5];
  const float* b_head = (const float*)d_in[6];
  float* out = (float*)d_out;

  char* ws = (char*)d_ws;
  // persistent layout
  u16*  Lh     = (u16*)(ws + 0);                    // 512 KB: [8][2][64][256] bf16
  int*  pflag  = (int*)(ws + 512 * 1024);           // 256 x 64B
  int*  lhflag = (int*)(ws + 528 * 1024);           // 256 x 64B
  int*  xcdcnt = (int*)(ws + 544 * 1024);           // 8 x 64B
  u16*  Pbuf   = (u16*)(ws + (1ull << 20));         // 16 MB: [8 x][2 p] x 1MB blocks
  u16*  wihb   = (u16*)(ws + (17ull << 20));        // 16 MB
  u16*  xbT    = (u16*)(ws + (33ull << 20));        // 64 MB

  // fallback layout (only used when ws tiny)
  u16*  h0    = (u16*)(ws + 0);
  u16*  h1    = (u16*)(ws + 256 * 1024);
  float* cbuf = (float*)(ws + 512 * 1024);

  const size_t NEED1 = (97ull << 20);
  const size_t NEED0 = (33ull << 20);

  hipMemsetAsync(ws, 0, 1u << 20, stream);   // zero Lh + all flags (or h0/h1/cbuf)

  if (ws_size >= NEED0) {
    {
      const int n8 = (int)((size_t)GG * DD / 8);
      conv_wih_kernel<<<(n8 + 255) / 256, 256, 0, stream>>>(W_ih, wihb);
    }
    if (ws_size >= NEED1) {
      const int n8 = (int)((size_t)BB * TT * DD / 8);
      conv_xT_kernel<<<(n8 + 255) / 256, 256, 0, stream>>>(x, xbT);
      lstm_persistent<1><<<256, 512, 0, stream>>>(x, xbT, wihb, W_hh, b_ih, b_hh,
                                                  Lh, pflag, lhflag, xcdcnt, Pbuf);
    } else {
      lstm_persistent<0><<<256, 512, 0, stream>>>(x, xbT, wihb, W_hh, b_ih, b_hh,
                                                  Lh, pflag, lhflag, xcdcnt, Pbuf);
    }
    head_lh_kernel<<<64, 256, 0, stream>>>(Lh, W_head, b_head, out);
  } else {
    for (int t = 0; t < TT; ++t) {
      u16* hs = (t & 1) ? h1 : h0;
      u16* hd = (t & 1) ? h0 : h1;
      lstm_step_kernel<<<256, 512, 0, stream>>>(x, W_ih, W_hh, b_ih, b_hh, hs, hd, cbuf, t);
    }
    head_kernel<<<64, 256, 0, stream>>>(h0, W_head, b_head, out);
  }
}